// Round 15
// baseline (291.111 us; speedup 1.0000x reference)
//
#include <hip/hip_runtime.h>
#include <hip/hip_fp16.h>
#include <stdint.h>

typedef _Float16 f16;
typedef _Float16 f16x4 __attribute__((ext_vector_type(4)));
typedef _Float16 f16x8 __attribute__((ext_vector_type(8)));
typedef float f32x4 __attribute__((ext_vector_type(4)));

#define T_STEPS 200
#define LOG2E 1.4426950408889634f
#define TWOLOG2E 2.8853900817779268f
#define GSTRIDE (512 * 512)   // f16 elements per time step of gi
#define OSTRIDE (512 * 256)   // f32 elements per time step of out
#define ATT_STRIDE 204        // floats per att_s row (odd 16B-chunk count)

#define MFMA16(a,b,c) __builtin_amdgcn_mfma_f32_16x16x32_f16((a),(b),(c),0,0,0)

__device__ __forceinline__ f16x8 cvt_f16x8s(const float4 lo, const float4 hi, float s) {
  f16x8 f;
  f[0]=(f16)(s*lo.x); f[1]=(f16)(s*lo.y); f[2]=(f16)(s*lo.z); f[3]=(f16)(s*lo.w);
  f[4]=(f16)(s*hi.x); f[5]=(f16)(s*hi.y); f[6]=(f16)(s*hi.z); f[7]=(f16)(s*hi.w);
  return f;
}
__device__ __forceinline__ f16x8 cvt_f16x8(const float4 lo, const float4 hi) {
  return cvt_f16x8s(lo, hi, 1.f);
}
__device__ __forceinline__ f16x4 cvt_f16x4v(const f32x4 v) {
  f16x4 f; f[0]=(f16)v[0]; f[1]=(f16)v[1]; f[2]=(f16)v[2]; f[3]=(f16)v[3]; return f;
}

// ---------------------------------------------------------------------------
// Kernel 1: gi stored f16 aliased into d_out, permuted so each gru thread
// reads ONE contiguous 16B chunk (8 f16: [gr e0..3, gn e0..3]) per step:
//   chunk addr (f16) = ((t*32 + blk)*16 + wv)*512 + (kq*16 + r)*8 + gate*4
//   gr pre-scaled by -log2e (sigmoid), gn pre-scaled by 2*log2e (tanh).
// W_ih rows: r gate = [0,256), n gate = [512,768).
// ---------------------------------------------------------------------------
__global__ __launch_bounds__(512, 2) void gi_kernel(
    const float* __restrict__ x,
    const int*   __restrict__ lengths,
    const float* __restrict__ w_ih,
    const float* __restrict__ b_ih,
    const float* __restrict__ b_hh,
    f16*         __restrict__ gi)
{
  const int m0 = blockIdx.x * 256;
  const int t  = m0 >> 9;
  const int bhalf = m0 & 511;          // 0 or 256
  if (t >= lengths[bhalf]) return;     // whole half-slice dead

  int nlive = 0;
  while (nlive < 16 && t < lengths[bhalf + nlive * 16]) ++nlive;

  __shared__ __align__(16) f16 xs[2][16 * 264];

  const int tid  = threadIdx.x;
  const int wave = tid >> 6;
  const int lane = tid & 63;
  const int cl   = lane & 15;
  const int kq   = lane >> 4;
  const int kk   = kq * 8;
  const float kscale = (wave < 4) ? -LOG2E : TWOLOG2E;

  f16x8 wf[4][8];
  float bias[4][4];
#pragma unroll
  for (int ct = 0; ct < 4; ++ct) {
    const int crow = wave * 64 + ct * 16 + cl;
    const int srow = (wave < 4) ? crow : (256 + crow);   // n gate rows 512+
    const float* p = w_ih + (size_t)srow * 256 + kk;
#pragma unroll
    for (int kt = 0; kt < 8; ++kt)
      wf[ct][kt] = cvt_f16x8(*(const float4*)(p + kt * 32),
                             *(const float4*)(p + kt * 32 + 4));
    const int cb = wave * 64 + ct * 16 + kq * 4;
    if (wave < 4) {
      float4 bi = *(const float4*)(b_ih + cb);
      float4 bh = *(const float4*)(b_hh + cb);
      bias[ct][0] = bi.x + bh.x; bias[ct][1] = bi.y + bh.y;
      bias[ct][2] = bi.z + bh.z; bias[ct][3] = bi.w + bh.w;
    } else {
      float4 bi = *(const float4*)(b_ih + 256 + cb);
      bias[ct][0] = bi.x; bias[ct][1] = bi.y;
      bias[ct][2] = bi.z; bias[ct][3] = bi.w;
    }
  }

  const int wv0   = (wave & 3) * 4;          // + ct
  const int gate4 = (wave >= 4) ? 4 : 0;

  f32x4 g[2];
#pragma unroll
  for (int i = 0; i < 2; ++i) {
    int q = i * 512 + tid; int r = q >> 6; int kc = (q & 63) * 4;
    g[i] = __builtin_nontemporal_load(
        (const f32x4*)(x + (size_t)(m0 + r) * 256 + kc));
  }
#pragma unroll
  for (int i = 0; i < 2; ++i) {
    int q = i * 512 + tid; int r = q >> 6; int kc = (q & 63) * 4;
    *(f16x4*)(&xs[0][r * 264 + kc]) = cvt_f16x4v(g[i]);
  }
  __syncthreads();

  for (int ms = 0; ms < nlive; ++ms) {
    const int buf = ms & 1;
    const bool more = (ms + 1) < nlive;
    if (more) {
#pragma unroll
      for (int i = 0; i < 2; ++i) {
        int q = i * 512 + tid; int r = q >> 6; int kc = (q & 63) * 4;
        g[i] = __builtin_nontemporal_load(
            (const f32x4*)(x + (size_t)(m0 + (ms + 1) * 16 + r) * 256 + kc));
      }
    }
    f32x4 acc[4];
#pragma unroll
    for (int ct = 0; ct < 4; ++ct) acc[ct] = (f32x4){0.f, 0.f, 0.f, 0.f};
#pragma unroll
    for (int kt = 0; kt < 8; ++kt) {
      f16x8 bx = *(const f16x8*)(&xs[buf][cl * 264 + kt * 32 + kk]);
#pragma unroll
      for (int ct = 0; ct < 4; ++ct)
        acc[ct] = MFMA16(wf[ct][kt], bx, acc[ct]);
    }
    const int blk = (bhalf >> 4) + ms;     // batch-block of 16 rows
    const size_t base = ((size_t)t * 32 + blk) * 8192
                      + (size_t)(kq * 16 + cl) * 8 + gate4;
#pragma unroll
    for (int ct = 0; ct < 4; ++ct) {
      f16x4 v;
#pragma unroll
      for (int e = 0; e < 4; ++e)
        v[e] = (f16)(kscale * (acc[ct][e] + bias[ct][e]));
      *(f16x4*)(gi + base + (size_t)(wv0 + ct) * 512) = v;
    }
    if (more) {
#pragma unroll
      for (int i = 0; i < 2; ++i) {
        int q = i * 512 + tid; int r = q >> 6; int kc = (q & 63) * 4;
        *(f16x4*)(&xs[buf ^ 1][r * 264 + kc]) = cvt_f16x4v(g[i]);
      }
    }
    __syncthreads();
  }
}

// ---------------------------------------------------------------------------
// Kernel 2: recurrence. 32 blocks x 16 rows, 16 waves (1024 thr, 4/SIMD).
// r13 base + vectorized epilogue:
//  - W_hh fragments pre-scaled (whr *= -log2e, whn *= 2log2e)
//  - epilogue on f32x4 ext-vectors (packed math; trans stay scalar)
//  - h ds_write issued before the out store
// ---------------------------------------------------------------------------
#define GRU_BODY(T, HSR, HSW, Qu, Qd, LD, BAR)                                 \
  {                                                                            \
    if (LD) { Qd = *(const f16x8*)gp; gp += GSTRIDE; }                         \
    f32x4 ar = (f32x4){0.f,0.f,0.f,0.f}, an = ar;                              \
    _Pragma("unroll")                                                          \
    for (int kt = 0; kt < 8; ++kt) {                                           \
      f16x8 hf = *(const f16x8*)(&HSR[r * 264 + kt * 32 + kk]);                \
      ar = MFMA16(whr[kt], hf, ar);                                            \
      an = MFMA16(whn[kt], hf, an);                                            \
    }                                                                          \
    const bool live = (T) < len;                                               \
    f32x4 grv, gnv;                                                            \
    _Pragma("unroll")                                                          \
    for (int e = 0; e < 4; ++e) { grv[e] = (float)Qu[e]; gnv[e] = (float)Qu[4 + e]; } \
    const f32x4 pre = ar + grv;                                                \
    f32x4 e2v;                                                                 \
    _Pragma("unroll")                                                          \
    for (int e = 0; e < 4; ++e) e2v[e] = __builtin_amdgcn_exp2f(pre[e]);       \
    const f32x4 d1 = e2v + 1.f;                                                \
    f32x4 rstv;                                                                \
    _Pragma("unroll")                                                          \
    for (int e = 0; e < 4; ++e) rstv[e] = __builtin_amdgcn_rcpf(d1[e]);        \
    const f32x4 hnv = an + bhn2v;                                              \
    const f32x4 q2 = __builtin_elementwise_fma(rstv, hnv, gnv);                \
    f32x4 env;                                                                 \
    _Pragma("unroll")                                                          \
    for (int e = 0; e < 4; ++e) env[e] = __builtin_amdgcn_exp2f(q2[e]);        \
    const f32x4 d2 = env + 1.f;                                                \
    f32x4 rv;                                                                  \
    _Pragma("unroll")                                                          \
    for (int e = 0; e < 4; ++e) rv[e] = __builtin_amdgcn_rcpf(d2[e]);          \
    const f32x4 ns = __builtin_elementwise_fma(rv, m2v, onev);                 \
    const f32x4 hy = __builtin_elementwise_fma(av4, ns - hcv, hcv);            \
    hcv = hy;                                   /* att==0 past len -> frozen */\
    f16x4 hv;                                                                  \
    _Pragma("unroll")                                                          \
    for (int e = 0; e < 4; ++e) hv[e] = (f16)hy[e];                            \
    *(f16x4*)(&HSW[r * 264 + jbase]) = hv;                                     \
    f32x4 sv;                                                                  \
    _Pragma("unroll")                                                          \
    for (int e = 0; e < 4; ++e) sv[e] = live ? hy[e] : 0.f;                    \
    __builtin_nontemporal_store(sv, (f32x4*)op);                               \
    op += OSTRIDE;                                                             \
    if (BAR) {                                                                 \
      asm volatile("s_waitcnt lgkmcnt(0)" ::: "memory");                       \
      __builtin_amdgcn_s_barrier();                                            \
    }                                                                          \
  }

__global__ __launch_bounds__(1024, 4) void gru_kernel(
    const float* __restrict__ att,
    const int*   __restrict__ lengths,
    const float* __restrict__ h0,
    const float* __restrict__ w_hh,
    const float* __restrict__ b_hh,
    float*       __restrict__ out)
{
  const f16* gi = (const f16*)out;   // aliased precomputed gi (permuted chunks)
  const int blk  = blockIdx.x;
  const int bb   = blk * 16;
  const int tid  = threadIdx.x;
  const int w    = tid >> 6;         // 0..15
  const int lane = tid & 63;
  const int r    = lane & 15;        // thread's batch row (local)
  const int kq   = lane >> 4;
  const int kk   = kq * 8;
  const int jbase = w * 16 + kq * 4; // thread's 4 output cols

  __shared__ __align__(16) f16   hs0[16 * 264];
  __shared__ __align__(16) f16   hs1[16 * 264];
  __shared__ __align__(16) float att_s[16 * ATT_STRIDE];   // [r][t]

  const f32x4 m2v  = (f32x4){-2.f, -2.f, -2.f, -2.f};
  const f32x4 onev = (f32x4){1.f, 1.f, 1.f, 1.f};

  // resident W_hh A-frags, PRE-SCALED: whr *= -log2e, whn *= 2log2e
  f16x8 whr[8], whn[8];
  {
    const int jrow = w * 16 + r;
    const float* pr = w_hh + (size_t)jrow * 256 + kk;
    const float* pn = w_hh + (size_t)(512 + jrow) * 256 + kk;
#pragma unroll
    for (int kt = 0; kt < 8; ++kt) {
      whr[kt] = cvt_f16x8s(*(const float4*)(pr + kt * 32),
                           *(const float4*)(pr + kt * 32 + 4), -LOG2E);
      whn[kt] = cvt_f16x8s(*(const float4*)(pn + kt * 32),
                           *(const float4*)(pn + kt * 32 + 4), TWOLOG2E);
    }
  }

  f32x4 bhn2v;
  {
    float4 bn = *(const float4*)(b_hh + 512 + jbase);
    bhn2v[0] = TWOLOG2E * bn.x; bhn2v[1] = TWOLOG2E * bn.y;
    bhn2v[2] = TWOLOG2E * bn.z; bhn2v[3] = TWOLOG2E * bn.w;
  }

  const int len = lengths[bb + r];

  // stage att as [r][t], pre-zeroed beyond each row's length
  for (int i = tid; i < T_STEPS * 16; i += 1024) {
    const int tt = i >> 4, rr = i & 15;
    const float a = att[(size_t)tt * 512 + bb + rr];
    att_s[rr * ATT_STRIDE + tt] = (tt < lengths[bb + rr]) ? a : 0.f;
  }

  // h carry in f32 regs + f16 copy to hs0
  f32x4 hcv;
  {
    float4 h4 = *(const float4*)(h0 + (size_t)(bb + r) * 256 + jbase);
    hcv[0] = h4.x; hcv[1] = h4.y; hcv[2] = h4.z; hcv[3] = h4.w;
    f16x4 hv; hv[0] = (f16)h4.x; hv[1] = (f16)h4.y; hv[2] = (f16)h4.z; hv[3] = (f16)h4.w;
    *(f16x4*)(&hs0[r * 264 + jbase]) = hv;
  }

  // prefetch t=0 (set A); running pointer at t=1 (distance-1)
  const size_t gb0 = (size_t)blk * 8192 + (size_t)w * 512 + (size_t)(kq * 16 + r) * 8;
  const f16* gp = gi + gb0 + (size_t)GSTRIDE;
  f16x8 qA = *(const f16x8*)(gi + gb0);
  f16x8 qB;
  float* op = out + ((size_t)bb + r) * 256 + jbase;
  __syncthreads();

  // main loop: bodies 0..195 (all prefetches in-bounds)
  for (int t = 0; t < 196; t += 2) {
    const float2 av2 = *(const float2*)(&att_s[r * ATT_STRIDE + t]);
    {
      const f32x4 av4 = (f32x4){av2.x, av2.x, av2.x, av2.x};
      GRU_BODY(t, hs0, hs1, qA, qB, 1, 1)
    }
    {
      const f32x4 av4 = (f32x4){av2.y, av2.y, av2.y, av2.y};
      GRU_BODY(t + 1, hs1, hs0, qB, qA, 1, 1)
    }
  }
  // tail: bodies 196..199 (body 199: no load, no barrier)
  {
    const float2 avA = *(const float2*)(&att_s[r * ATT_STRIDE + 196]);
    {
      const f32x4 av4 = (f32x4){avA.x, avA.x, avA.x, avA.x};
      GRU_BODY(196, hs0, hs1, qA, qB, 1, 1)
    }
    {
      const f32x4 av4 = (f32x4){avA.y, avA.y, avA.y, avA.y};
      GRU_BODY(197, hs1, hs0, qB, qA, 1, 1)
    }
    const float2 avB = *(const float2*)(&att_s[r * ATT_STRIDE + 198]);
    {
      const f32x4 av4 = (f32x4){avB.x, avB.x, avB.x, avB.x};
      GRU_BODY(198, hs0, hs1, qA, qB, 1, 1)
    }
    {
      const f32x4 av4 = (f32x4){avB.y, avB.y, avB.y, avB.y};
      GRU_BODY(199, hs1, hs0, qB, qA, 0, 0)
    }
  }
}

extern "C" void kernel_launch(void* const* d_in, const int* in_sizes, int n_in,
                              void* d_out, int out_size, void* d_ws, size_t ws_size,
                              hipStream_t stream) {
  const float* x       = (const float*)d_in[0];
  const float* att     = (const float*)d_in[1];
  const int*   lengths = (const int*)d_in[2];
  const float* h0      = (const float*)d_in[3];
  const float* w_ih    = (const float*)d_in[4];
  const float* w_hh    = (const float*)d_in[5];
  const float* b_ih    = (const float*)d_in[6];
  const float* b_hh    = (const float*)d_in[7];
  float* out = (float*)d_out;

  (void)in_sizes; (void)n_in; (void)out_size; (void)d_ws; (void)ws_size;

  hipLaunchKernelGGL(gi_kernel, dim3(400), dim3(512), 0, stream,
                     x, lengths, w_ih, b_ih, b_hh, (f16*)out);
  hipLaunchKernelGGL(gru_kernel, dim3(32), dim3(1024), 0, stream,
                     att, lengths, h0, w_hh, b_hh, out);
}

// Round 16
// 285.139 us; speedup vs baseline: 1.0209x; 1.0209x over previous
//
#include <hip/hip_runtime.h>
#include <hip/hip_fp16.h>
#include <stdint.h>

typedef _Float16 f16;
typedef _Float16 f16x4 __attribute__((ext_vector_type(4)));
typedef _Float16 f16x8 __attribute__((ext_vector_type(8)));
typedef float f32x4 __attribute__((ext_vector_type(4)));

#define T_STEPS 200
#define LOG2E 1.4426950408889634f
#define TWOLOG2E 2.8853900817779268f
#define GSTRIDE (512 * 512)   // f16 elements per time step of gi
#define OSTRIDE (512 * 256)   // f32 elements per time step of out
#define ATT_STRIDE 204        // floats per att_s row (odd 16B-chunk count)
#define HBUF 4224             // f16 elements per h buffer (16*264)

#define MFMA16(a,b,c) __builtin_amdgcn_mfma_f32_16x16x32_f16((a),(b),(c),0,0,0)

__device__ __forceinline__ f16x8 cvt_f16x8s(const float4 lo, const float4 hi, float s) {
  f16x8 f;
  f[0]=(f16)(s*lo.x); f[1]=(f16)(s*lo.y); f[2]=(f16)(s*lo.z); f[3]=(f16)(s*lo.w);
  f[4]=(f16)(s*hi.x); f[5]=(f16)(s*hi.y); f[6]=(f16)(s*hi.z); f[7]=(f16)(s*hi.w);
  return f;
}
__device__ __forceinline__ f16x8 cvt_f16x8(const float4 lo, const float4 hi) {
  return cvt_f16x8s(lo, hi, 1.f);
}
__device__ __forceinline__ f16x4 cvt_f16x4v(const f32x4 v) {
  f16x4 f; f[0]=(f16)v[0]; f[1]=(f16)v[1]; f[2]=(f16)v[2]; f[3]=(f16)v[3]; return f;
}

// ---------------------------------------------------------------------------
// Kernel 1: gi stored f16 aliased into d_out, permuted so each gru thread
// reads ONE contiguous 16B chunk (8 f16: [gr e0..3, gn e0..3]) per step:
//   chunk addr (f16) = ((t*32 + blk)*16 + wv)*512 + (kq*16 + r)*8 + gate*4
//   gr pre-scaled by -log2e (sigmoid), gn pre-scaled by 2*log2e (tanh).
// W_ih rows: r gate = [0,256), n gate = [512,768).
// ---------------------------------------------------------------------------
__global__ __launch_bounds__(512, 2) void gi_kernel(
    const float* __restrict__ x,
    const int*   __restrict__ lengths,
    const float* __restrict__ w_ih,
    const float* __restrict__ b_ih,
    const float* __restrict__ b_hh,
    f16*         __restrict__ gi)
{
  const int m0 = blockIdx.x * 256;
  const int t  = m0 >> 9;
  const int bhalf = m0 & 511;          // 0 or 256
  if (t >= lengths[bhalf]) return;     // whole half-slice dead

  int nlive = 0;
  while (nlive < 16 && t < lengths[bhalf + nlive * 16]) ++nlive;

  __shared__ __align__(16) f16 xs[2][16 * 264];

  const int tid  = threadIdx.x;
  const int wave = tid >> 6;
  const int lane = tid & 63;
  const int cl   = lane & 15;
  const int kq   = lane >> 4;
  const int kk   = kq * 8;
  const float kscale = (wave < 4) ? -LOG2E : TWOLOG2E;

  f16x8 wf[4][8];
  float bias[4][4];
#pragma unroll
  for (int ct = 0; ct < 4; ++ct) {
    const int crow = wave * 64 + ct * 16 + cl;
    const int srow = (wave < 4) ? crow : (256 + crow);   // n gate rows 512+
    const float* p = w_ih + (size_t)srow * 256 + kk;
#pragma unroll
    for (int kt = 0; kt < 8; ++kt)
      wf[ct][kt] = cvt_f16x8(*(const float4*)(p + kt * 32),
                             *(const float4*)(p + kt * 32 + 4));
    const int cb = wave * 64 + ct * 16 + kq * 4;
    if (wave < 4) {
      float4 bi = *(const float4*)(b_ih + cb);
      float4 bh = *(const float4*)(b_hh + cb);
      bias[ct][0] = bi.x + bh.x; bias[ct][1] = bi.y + bh.y;
      bias[ct][2] = bi.z + bh.z; bias[ct][3] = bi.w + bh.w;
    } else {
      float4 bi = *(const float4*)(b_ih + 256 + cb);
      bias[ct][0] = bi.x; bias[ct][1] = bi.y;
      bias[ct][2] = bi.z; bias[ct][3] = bi.w;
    }
  }

  const int wv0   = (wave & 3) * 4;          // + ct
  const int gate4 = (wave >= 4) ? 4 : 0;

  f32x4 g[2];
#pragma unroll
  for (int i = 0; i < 2; ++i) {
    int q = i * 512 + tid; int r = q >> 6; int kc = (q & 63) * 4;
    g[i] = __builtin_nontemporal_load(
        (const f32x4*)(x + (size_t)(m0 + r) * 256 + kc));
  }
#pragma unroll
  for (int i = 0; i < 2; ++i) {
    int q = i * 512 + tid; int r = q >> 6; int kc = (q & 63) * 4;
    *(f16x4*)(&xs[0][r * 264 + kc]) = cvt_f16x4v(g[i]);
  }
  __syncthreads();

  for (int ms = 0; ms < nlive; ++ms) {
    const int buf = ms & 1;
    const bool more = (ms + 1) < nlive;
    if (more) {
#pragma unroll
      for (int i = 0; i < 2; ++i) {
        int q = i * 512 + tid; int r = q >> 6; int kc = (q & 63) * 4;
        g[i] = __builtin_nontemporal_load(
            (const f32x4*)(x + (size_t)(m0 + (ms + 1) * 16 + r) * 256 + kc));
      }
    }
    f32x4 acc[4];
#pragma unroll
    for (int ct = 0; ct < 4; ++ct) acc[ct] = (f32x4){0.f, 0.f, 0.f, 0.f};
#pragma unroll
    for (int kt = 0; kt < 8; ++kt) {
      f16x8 bx = *(const f16x8*)(&xs[buf][cl * 264 + kt * 32 + kk]);
#pragma unroll
      for (int ct = 0; ct < 4; ++ct)
        acc[ct] = MFMA16(wf[ct][kt], bx, acc[ct]);
    }
    const int blk = (bhalf >> 4) + ms;     // batch-block of 16 rows
    const size_t base = ((size_t)t * 32 + blk) * 8192
                      + (size_t)(kq * 16 + cl) * 8 + gate4;
#pragma unroll
    for (int ct = 0; ct < 4; ++ct) {
      f16x4 v;
#pragma unroll
      for (int e = 0; e < 4; ++e)
        v[e] = (f16)(kscale * (acc[ct][e] + bias[ct][e]));
      *(f16x4*)(gi + base + (size_t)(wv0 + ct) * 512) = v;
    }
    if (more) {
#pragma unroll
      for (int i = 0; i < 2; ++i) {
        int q = i * 512 + tid; int r = q >> 6; int kc = (q & 63) * 4;
        *(f16x4*)(&xs[buf ^ 1][r * 264 + kc]) = cvt_f16x4v(g[i]);
      }
    }
    __syncthreads();
  }
}

// ---------------------------------------------------------------------------
// Kernel 2: recurrence. 32 blocks x 16 rows, 16 waves (1024 thr, 4/SIMD).
// r13/r15 base + address-overhead strip:
//  - flat h double-buffer: one read-base + one write-base VGPR, all LDS
//    accesses via compile-time imm offsets (buf*8448B + kt*64B)
//  - out store issued AFTER the barrier (off the pre-barrier critical path)
//  - unroll-4, one f32x4 att read per 4 steps
//  - pre-scaled W_hh frags, vectorized epilogue, nt stores, dist-1 prefetch
// ---------------------------------------------------------------------------
#define GRU_BODY(T, BUFR, BUFW, Qu, Qd, AV, LD, BAR)                           \
  {                                                                            \
    if (LD) { Qd = *(const f16x8*)gp; gp += GSTRIDE; }                         \
    f32x4 ar = (f32x4){0.f,0.f,0.f,0.f}, an = ar;                              \
    _Pragma("unroll")                                                          \
    for (int kt = 0; kt < 8; ++kt) {                                           \
      f16x8 hf = *(const f16x8*)(hb + (BUFR) * HBUF + kt * 32);                \
      ar = MFMA16(whr[kt], hf, ar);                                            \
      an = MFMA16(whn[kt], hf, an);                                            \
    }                                                                          \
    const bool live = (T) < len;                                               \
    const f32x4 av4 = (f32x4){AV, AV, AV, AV};                                 \
    f32x4 grv, gnv;                                                            \
    _Pragma("unroll")                                                          \
    for (int e = 0; e < 4; ++e) { grv[e] = (float)Qu[e]; gnv[e] = (float)Qu[4 + e]; } \
    const f32x4 pre = ar + grv;                                                \
    f32x4 e2v;                                                                 \
    _Pragma("unroll")                                                          \
    for (int e = 0; e < 4; ++e) e2v[e] = __builtin_amdgcn_exp2f(pre[e]);       \
    const f32x4 d1 = e2v + 1.f;                                                \
    f32x4 rstv;                                                                \
    _Pragma("unroll")                                                          \
    for (int e = 0; e < 4; ++e) rstv[e] = __builtin_amdgcn_rcpf(d1[e]);        \
    const f32x4 hnv = an + bhn2v;                                              \
    const f32x4 q2 = __builtin_elementwise_fma(rstv, hnv, gnv);                \
    f32x4 env;                                                                 \
    _Pragma("unroll")                                                          \
    for (int e = 0; e < 4; ++e) env[e] = __builtin_amdgcn_exp2f(q2[e]);        \
    const f32x4 d2 = env + 1.f;                                                \
    f32x4 rv;                                                                  \
    _Pragma("unroll")                                                          \
    for (int e = 0; e < 4; ++e) rv[e] = __builtin_amdgcn_rcpf(d2[e]);          \
    const f32x4 ns = __builtin_elementwise_fma(rv, m2v, onev);                 \
    const f32x4 hy = __builtin_elementwise_fma(av4, ns - hcv, hcv);            \
    hcv = hy;                                   /* att==0 past len -> frozen */\
    f16x4 hv;                                                                  \
    _Pragma("unroll")                                                          \
    for (int e = 0; e < 4; ++e) hv[e] = (f16)hy[e];                            \
    *(f16x4*)(hw + (BUFW) * HBUF) = hv;                                        \
    f32x4 sv;                                                                  \
    _Pragma("unroll")                                                          \
    for (int e = 0; e < 4; ++e) sv[e] = live ? hy[e] : 0.f;                    \
    if (BAR) {                                                                 \
      asm volatile("s_waitcnt lgkmcnt(0)" ::: "memory");                       \
      __builtin_amdgcn_s_barrier();                                            \
    }                                                                          \
    __builtin_nontemporal_store(sv, (f32x4*)op);   /* post-barrier */          \
    op += OSTRIDE;                                                             \
  }

__global__ __launch_bounds__(1024, 4) void gru_kernel(
    const float* __restrict__ att,
    const int*   __restrict__ lengths,
    const float* __restrict__ h0,
    const float* __restrict__ w_hh,
    const float* __restrict__ b_hh,
    float*       __restrict__ out)
{
  const f16* gi = (const f16*)out;   // aliased precomputed gi (permuted chunks)
  const int blk  = blockIdx.x;
  const int bb   = blk * 16;
  const int tid  = threadIdx.x;
  const int w    = tid >> 6;         // 0..15
  const int lane = tid & 63;
  const int r    = lane & 15;        // thread's batch row (local)
  const int kq   = lane >> 4;
  const int kk   = kq * 8;
  const int jbase = w * 16 + kq * 4; // thread's 4 output cols

  __shared__ __align__(16) f16   hsbuf[2 * HBUF];          // flat double buffer
  __shared__ __align__(16) float att_s[16 * ATT_STRIDE];   // [r][t]

  const f32x4 m2v  = (f32x4){-2.f, -2.f, -2.f, -2.f};
  const f32x4 onev = (f32x4){1.f, 1.f, 1.f, 1.f};

  // single base pointers: all per-step LDS accesses use imm offsets off these
  const f16* hb = hsbuf + r * 264 + kk;     // read base (buf 0)
  f16*       hw = hsbuf + r * 264 + jbase;  // write base (buf 0)

  // resident W_hh A-frags, PRE-SCALED: whr *= -log2e, whn *= 2log2e
  f16x8 whr[8], whn[8];
  {
    const int jrow = w * 16 + r;
    const float* pr = w_hh + (size_t)jrow * 256 + kk;
    const float* pn = w_hh + (size_t)(512 + jrow) * 256 + kk;
#pragma unroll
    for (int kt = 0; kt < 8; ++kt) {
      whr[kt] = cvt_f16x8s(*(const float4*)(pr + kt * 32),
                           *(const float4*)(pr + kt * 32 + 4), -LOG2E);
      whn[kt] = cvt_f16x8s(*(const float4*)(pn + kt * 32),
                           *(const float4*)(pn + kt * 32 + 4), TWOLOG2E);
    }
  }

  f32x4 bhn2v;
  {
    float4 bn = *(const float4*)(b_hh + 512 + jbase);
    bhn2v[0] = TWOLOG2E * bn.x; bhn2v[1] = TWOLOG2E * bn.y;
    bhn2v[2] = TWOLOG2E * bn.z; bhn2v[3] = TWOLOG2E * bn.w;
  }

  const int len = lengths[bb + r];

  // stage att as [r][t], pre-zeroed beyond each row's length
  for (int i = tid; i < T_STEPS * 16; i += 1024) {
    const int tt = i >> 4, rr = i & 15;
    const float a = att[(size_t)tt * 512 + bb + rr];
    att_s[rr * ATT_STRIDE + tt] = (tt < lengths[bb + rr]) ? a : 0.f;
  }

  // h carry in f32 regs + f16 copy to buffer 0
  f32x4 hcv;
  {
    float4 h4 = *(const float4*)(h0 + (size_t)(bb + r) * 256 + jbase);
    hcv[0] = h4.x; hcv[1] = h4.y; hcv[2] = h4.z; hcv[3] = h4.w;
    f16x4 hv; hv[0] = (f16)h4.x; hv[1] = (f16)h4.y; hv[2] = (f16)h4.z; hv[3] = (f16)h4.w;
    *(f16x4*)hw = hv;
  }

  // prefetch t=0 (set A); running pointer at t=1 (distance-1)
  const size_t gb0 = (size_t)blk * 8192 + (size_t)w * 512 + (size_t)(kq * 16 + r) * 8;
  const f16* gp = gi + gb0 + (size_t)GSTRIDE;
  f16x8 qA = *(const f16x8*)(gi + gb0);
  f16x8 qB;
  float* op = out + ((size_t)bb + r) * 256 + jbase;
  __syncthreads();

  // main loop: bodies 0..195, unroll 4 (all prefetches in-bounds)
  for (int t = 0; t < 196; t += 4) {
    const f32x4 av4r = *(const f32x4*)(&att_s[r * ATT_STRIDE + t]);
    GRU_BODY(t,     0, 1, qA, qB, av4r[0], 1, 1)
    GRU_BODY(t + 1, 1, 0, qB, qA, av4r[1], 1, 1)
    GRU_BODY(t + 2, 0, 1, qA, qB, av4r[2], 1, 1)
    GRU_BODY(t + 3, 1, 0, qB, qA, av4r[3], 1, 1)
  }
  // tail: bodies 196..199 (body 199: no load, no barrier)
  {
    const f32x4 av4r = *(const f32x4*)(&att_s[r * ATT_STRIDE + 196]);
    GRU_BODY(196, 0, 1, qA, qB, av4r[0], 1, 1)
    GRU_BODY(197, 1, 0, qB, qA, av4r[1], 1, 1)
    GRU_BODY(198, 0, 1, qA, qB, av4r[2], 1, 1)
    GRU_BODY(199, 1, 0, qB, qA, av4r[3], 0, 0)
  }
}

extern "C" void kernel_launch(void* const* d_in, const int* in_sizes, int n_in,
                              void* d_out, int out_size, void* d_ws, size_t ws_size,
                              hipStream_t stream) {
  const float* x       = (const float*)d_in[0];
  const float* att     = (const float*)d_in[1];
  const int*   lengths = (const int*)d_in[2];
  const float* h0      = (const float*)d_in[3];
  const float* w_ih    = (const float*)d_in[4];
  const float* w_hh    = (const float*)d_in[5];
  const float* b_ih    = (const float*)d_in[6];
  const float* b_hh    = (const float*)d_in[7];
  float* out = (float*)d_out;

  (void)in_sizes; (void)n_in; (void)out_size; (void)d_ws; (void)ws_size;

  hipLaunchKernelGGL(gi_kernel, dim3(400), dim3(512), 0, stream,
                     x, lengths, w_ih, b_ih, b_hh, (f16*)out);
  hipLaunchKernelGGL(gru_kernel, dim3(32), dim3(1024), 0, stream,
                     att, lengths, h0, w_hh, b_hh, out);
}